// Round 7
// baseline (455.943 us; speedup 1.0000x reference)
//
#include <hip/hip_runtime.h>
#include <math.h>

// LambdaLayer round 7: register-chained k_main using ONLY mfma_f32_16x16x32_bf16.
// (Round 6 lesson: __has_builtin is false for aux-target builtins in the HOST pass,
//  so builtin-name fallbacks break host parsing. Stick to proven builtins.)
// A-step: block-diag q, 2 chained mfma per (m-frag): P[m][col=(nl,h)], m=l4*4+reg.
// B-step: pair two m-frags' P into one K=32 B-operand (k-slots relabeled), A-op = vb
//         from swizzled LDS. 12 MFMAs + 1 barrier + 1 vmcnt(0) per m-tile of 64.
// Content term = zero-padded K=32 MFMA per v-frag in epilogue.

#define BB 32
#define DD 256
#define NPOS 1024
#define KDIM 16
#define HH 4
#define VV 64
#define F_EPS 1e-5f

typedef __attribute__((ext_vector_type(8))) short short8;   // 8 bf16
typedef __attribute__((ext_vector_type(4))) short s16x4;    // 4 bf16
typedef __attribute__((ext_vector_type(4))) float f32x4;
typedef unsigned short ushort_t;
typedef unsigned int uint_t;

typedef __attribute__((address_space(1))) const uint_t g32_t;
typedef __attribute__((address_space(3))) uint_t l32_t;

__device__ __forceinline__ void gload16(const void* g, void* l) {
    __builtin_amdgcn_global_load_lds((g32_t*)g, (l32_t*)l, 16, 0, 0);
}

__device__ __forceinline__ uint_t bfpack(float x, float y) {   // 2 f32 -> packed bf16 (RNE)
    uint_t ux = __float_as_uint(x), uy = __float_as_uint(y);
    ux = (ux + 0x7FFFu + ((ux >> 16) & 1u)) >> 16;
    uy = (uy + 0x7FFFu + ((uy >> 16) & 1u)) >> 16;
    return ux | (uy << 16);
}
__device__ __forceinline__ ushort_t f2bf(float x) {
    uint_t u = __float_as_uint(x);
    return (ushort_t)((u + 0x7FFFu + ((u >> 16) & 1u)) >> 16);
}
__device__ __forceinline__ float bflo(uint_t u) { return __uint_as_float(u << 16); }
__device__ __forceinline__ float bfhi(uint_t u) { return __uint_as_float(u & 0xFFFF0000u); }

#define MFMA32(a,b,c) __builtin_amdgcn_mfma_f32_16x16x32_bf16(a,b,c,0,0,0)

__device__ __forceinline__ s16x4 pack4(f32x4 p) {
    union { uint_t u[2]; s16x4 s; } r;
    r.u[0] = bfpack(p[0], p[1]);
    r.u[1] = bfpack(p[2], p[3]);
    return r.s;
}
__device__ __forceinline__ short8 cat4(s16x4 a, s16x4 b) {
    union { s16x4 h[2]; short8 v; } r;
    r.h[0] = a; r.h[1] = b;
    return r.v;
}

// ---------------- W concat + cvt ----------------
__global__ void k_wcvt(const float* __restrict__ Wq, const float* __restrict__ Wk,
                       const float* __restrict__ Wv, ushort_t* __restrict__ Wb) {
    int i = blockIdx.x*256 + threadIdx.x;
    int fi = i*8;
    int row = fi >> 8, col = fi & 255;
    const float* src;
    if (row < 16)      src = Wk + row*DD + col;
    else if (row < 80) src = Wv + (row-16)*DD + col;
    else               src = Wq + (row-80)*DD + col;
    float4 a = ((const float4*)src)[0], c = ((const float4*)src)[1];
    uint4 o;
    o.x = bfpack(a.x, a.y); o.y = bfpack(a.z, a.w);
    o.z = bfpack(c.x, c.y); o.w = bfpack(c.z, c.w);
    *(uint4*)(Wb + fi) = o;
}

// ---------------- K1: MFMA projection GEMM ----------------
__global__ __launch_bounds__(256) void k_projm(
        const float* __restrict__ x, const ushort_t* __restrict__ Wb,
        float* __restrict__ keys, float* __restrict__ vals, float* __restrict__ qrs) {
    const int b = blockIdx.x, nt = blockIdx.y;
    const int w = threadIdx.x >> 6, lane = threadIdx.x & 63;
    const int l15 = lane & 15, l4 = lane >> 4;
    const int n = nt*64 + w*16 + l15;

    const float* xr = x + ((size_t)b*NPOS + n)*DD + l4*8;
    float4 xa[8][2];
    #pragma unroll
    for (int ks = 0; ks < 8; ++ks) {
        xa[ks][0] = *(const float4*)(xr + ks*32);
        xa[ks][1] = *(const float4*)(xr + ks*32 + 4);
    }

    f32x4 acc[9];
    #pragma unroll
    for (int m = 0; m < 9; ++m) acc[m] = (f32x4){0.f,0.f,0.f,0.f};

    const ushort_t* wp = Wb + (size_t)l15*DD + l4*8;
    #pragma unroll
    for (int ks = 0; ks < 8; ++ks) {
        union { uint_t u[4]; short8 s8; } bu;
        bu.u[0] = bfpack(xa[ks][0].x, xa[ks][0].y);
        bu.u[1] = bfpack(xa[ks][0].z, xa[ks][0].w);
        bu.u[2] = bfpack(xa[ks][1].x, xa[ks][1].y);
        bu.u[3] = bfpack(xa[ks][1].z, xa[ks][1].w);
        #pragma unroll
        for (int m = 0; m < 9; ++m) {
            short8 wf = *(const short8*)(wp + (size_t)m*16*DD + ks*32);
            acc[m] = MFMA32(wf, bu.s8, acc[m]);
        }
    }

    #pragma unroll
    for (int m = 0; m < 9; ++m) {
        float* dst;
        int c0 = m*16 + l4*4;
        if (m == 0)      dst = keys + (size_t)b*KDIM*NPOS + (size_t)c0*NPOS;
        else if (m < 5)  dst = vals + (size_t)b*VV*NPOS   + (size_t)(c0-16)*NPOS;
        else             dst = qrs  + (size_t)b*VV*NPOS   + (size_t)(c0-80)*NPOS;
        #pragma unroll
        for (int i = 0; i < 4; ++i)
            dst[(size_t)i*NPOS + n] = acc[m][i];
    }
}

__global__ void k_zero(float* __restrict__ p, int nfl) {
    int i = blockIdx.x * 256 + threadIdx.x;
    if (i < nfl) p[i] = 0.f;
}

// ---------------- E -> E2 bf16 transposed tiles ----------------
// Tile T = ncg*16 + mt, elem = m*64 + s*32 + l4c*8 + j holds
// E[ncg*4 + s*2 + (l4c>>1)][mt*64+m][(l4c&1)*8+j]
__global__ void k_ecvt2(const float* __restrict__ E, ushort_t* __restrict__ E2) {
    size_t C = (size_t)blockIdx.x * 256 + threadIdx.x;   // 16B chunk id
    int c8 = (int)(C & 511);
    size_t T = C >> 9;
    int m  = c8 >> 3, s = (c8 >> 2) & 1, l4c = c8 & 3;
    int mt = (int)(T & 15);
    int ncg = (int)(T >> 4);
    int n = ncg*4 + s*2 + (l4c >> 1);
    int kd0 = (l4c & 1) * 8;
    const float* src = E + ((size_t)n*NPOS + mt*64 + m)*KDIM + kd0;
    float4 a = ((const float4*)src)[0], c = ((const float4*)src)[1];
    uint4 o;
    o.x = bfpack(a.x, a.y); o.y = bfpack(a.z, a.w);
    o.z = bfpack(c.x, c.y); o.w = bfpack(c.z, c.w);
    *(uint4*)(E2 + C*8) = o;
}

// ---------------- softmax ----------------
__global__ void k_softmax(float* __restrict__ keys) {
    const int wid  = (blockIdx.x * 256 + threadIdx.x) >> 6;
    const int lane = threadIdx.x & 63;
    float* row = keys + (size_t)wid * NPOS;
    float v[16];
    float mx = -1e30f;
    #pragma unroll
    for (int j = 0; j < 16; ++j) { v[j] = row[lane + 64*j]; mx = fmaxf(mx, v[j]); }
    #pragma unroll
    for (int off = 32; off >= 1; off >>= 1) mx = fmaxf(mx, __shfl_xor(mx, off));
    float s = 0.f;
    #pragma unroll
    for (int j = 0; j < 16; ++j) { v[j] = __expf(v[j] - mx); s += v[j]; }
    #pragma unroll
    for (int off = 32; off >= 1; off >>= 1) s += __shfl_xor(s, off);
    float inv = 1.f / s;
    #pragma unroll
    for (int j = 0; j < 16; ++j) row[lane + 64*j] = v[j] * inv;
}

// ---------------- value BN stats ----------------
__global__ void k_vstats(const float* __restrict__ vals, float* __restrict__ sv) {
    const int g = blockIdx.x, t = threadIdx.x;
    float s[4] = {0,0,0,0}, q[4] = {0,0,0,0};
    for (int r = g*32; r < g*32 + 32; ++r) {
        const float* row = vals + (size_t)r * NPOS;
        #pragma unroll
        for (int j = 0; j < 4; ++j) { float x = row[t + 256*j]; s[j] += x; q[j] += x*x; }
    }
    #pragma unroll
    for (int j = 0; j < 4; ++j) {
        atomicAdd(&sv[t + 256*j], s[j]);
        atomicAdd(&sv[1024 + t + 256*j], q[j]);
    }
}

__global__ void k_vfinal(float* __restrict__ sv, const float* __restrict__ gv,
                         const float* __restrict__ bv) {
    int m = blockIdx.x*256 + threadIdx.x;
    float mean = sv[m] * (1.f/2048.f);
    float var  = sv[1024+m] * (1.f/2048.f) - mean*mean;
    float sc = rsqrtf(var + F_EPS) * gv[m];
    sv[m] = sc;
    sv[1024+m] = bv[m] - mean*sc;
}

// ---------------- BN-apply + cvt: vals f32 -> vb_bf16 [b][v][m] ----------------
__global__ void k_vcvt(const float* __restrict__ vals, const float* __restrict__ sv,
                       ushort_t* __restrict__ vb) {
    int i = blockIdx.x*256 + threadIdx.x;
    int m0 = (i & 127) * 8;
    const float4* src = (const float4*)(vals + (size_t)i*8);
    float4 a = src[0], c = src[1];
    float4 s0 = *(const float4*)(sv + m0),        s1 = *(const float4*)(sv + m0 + 4);
    float4 h0 = *(const float4*)(sv + 1024 + m0), h1 = *(const float4*)(sv + 1024 + m0 + 4);
    a.x = a.x*s0.x + h0.x; a.y = a.y*s0.y + h0.y; a.z = a.z*s0.z + h0.z; a.w = a.w*s0.w + h0.w;
    c.x = c.x*s1.x + h1.x; c.y = c.y*s1.y + h1.y; c.z = c.z*s1.z + h1.z; c.w = c.w*s1.w + h1.w;
    uint4 o;
    o.x = bfpack(a.x, a.y); o.y = bfpack(a.z, a.w);
    o.z = bfpack(c.x, c.y); o.w = bfpack(c.z, c.w);
    *(uint4*)(vb + (size_t)i*8) = o;
}

// ---------------- query BN stats ----------------
__global__ void k_qstats(const float* __restrict__ qrs, float* __restrict__ sq) {
    const int kd = blockIdx.x >> 3, sub = blockIdx.x & 7;
    float s = 0.f, ss = 0.f;
    for (int b = sub*4; b < sub*4 + 4; ++b)
        for (int h = 0; h < HH; ++h) {
            const float* row = qrs + ((size_t)(b*KDIM*HH) + kd*4 + h) * NPOS;
            #pragma unroll
            for (int j = 0; j < 4; ++j) { float x = row[threadIdx.x + 256*j]; s += x; ss += x*x; }
        }
    #pragma unroll
    for (int off = 32; off >= 1; off >>= 1) { s += __shfl_xor(s, off); ss += __shfl_xor(ss, off); }
    __shared__ float red[8];
    int w = threadIdx.x >> 6, lane = threadIdx.x & 63;
    if (lane == 0) { red[w] = s; red[4+w] = ss; }
    __syncthreads();
    if (threadIdx.x == 0) atomicAdd(&sq[kd],    red[0]+red[1]+red[2]+red[3]);
    if (threadIdx.x == 1) atomicAdd(&sq[16+kd], red[4]+red[5]+red[6]+red[7]);
}

__global__ void k_qfinal(float* __restrict__ sq, const float* __restrict__ gq,
                         const float* __restrict__ bq) {
    int kd = threadIdx.x;
    const float inv = 1.f / 131072.f;
    float mean = sq[kd] * inv;
    float var  = sq[16+kd] * inv - mean*mean;
    float sc = rsqrtf(var + F_EPS) * gq[kd];
    sq[kd] = sc;
    sq[16+kd] = bq[kd] - mean*sc;
}

// ---------------- k_qT: BN-apply -> qd (block-diag) and qc ----------------
__global__ void k_qT(const float* __restrict__ qrs, const float* __restrict__ sq,
                     ushort_t* __restrict__ qd, ushort_t* __restrict__ qc) {
    __shared__ float tile[64][68];   // [c=kd*4+h][n_local]
    const int b = blockIdx.x >> 4, nt = blockIdx.x & 15;
    const int t = threadIdx.x;
    {
        int c = t >> 2, j0 = t & 3;
        const float4* src = (const float4*)(qrs + ((size_t)b*64 + c)*NPOS + nt*64);
        #pragma unroll
        for (int i = 0; i < 4; ++i) {
            float4 v = src[j0 + i*4];
            *(float4*)&tile[c][(j0 + i*4)*4] = v;
        }
    }
    __syncthreads();
    const int ncg_l = t >> 4, col = t & 15;
    const int ncg = nt*16 + ncg_l;
    const int n_local = ncg_l*4 + (col >> 2), h = col & 3;
    float q16[16];
    #pragma unroll
    for (int kd = 0; kd < 16; ++kd)
        q16[kd] = tile[kd*4 + h][n_local] * sq[kd] + sq[16 + kd];

    {
        uint_t wv[8];
        #pragma unroll
        for (int w2 = 0; w2 < 8; ++w2) wv[w2] = bfpack(q16[2*w2], q16[2*w2+1]);
        uint4* dst = (uint4*)(qc + (((size_t)b*256 + ncg)*16 + col)*16);
        dst[0] = make_uint4(wv[0], wv[1], wv[2], wv[3]);
        dst[1] = make_uint4(wv[4], wv[5], wv[6], wv[7]);
    }
    #pragma unroll
    for (int s = 0; s < 2; ++s) {
        uint_t wv[16];
        #pragma unroll
        for (int w2 = 0; w2 < 16; ++w2) {
            int nlk = w2 >> 3;
            int kd = (2*w2) & 15;
            wv[w2] = ((col >> 2) == s*2 + nlk) ? bfpack(q16[kd], q16[kd+1]) : 0u;
        }
        uint4* dst = (uint4*)(qd + ((((size_t)b*256 + ncg)*2 + s)*16 + col)*32);
        dst[0] = make_uint4(wv[0],  wv[1],  wv[2],  wv[3]);
        dst[1] = make_uint4(wv[4],  wv[5],  wv[6],  wv[7]);
        dst[2] = make_uint4(wv[8],  wv[9],  wv[10], wv[11]);
        dst[3] = make_uint4(wv[12], wv[13], wv[14], wv[15]);
    }
}

// ---------------- content lambda -> clb [b][v][16kd] ----------------
__global__ void k_cl(const float* __restrict__ sk, const ushort_t* __restrict__ vb,
                     ushort_t* __restrict__ clb) {
    const int b = blockIdx.x >> 4, kd = blockIdx.x & 15;
    __shared__ float skl[NPOS];
    __shared__ float red[256];
    const int t = threadIdx.x;
    const float* srow = sk + ((size_t)b*KDIM + kd) * NPOS;
    #pragma unroll
    for (int j = 0; j < 4; ++j) skl[t + 256*j] = srow[t + 256*j];
    __syncthreads();
    const int v = t >> 2, q = t & 3;
    const uint4* v4 = (const uint4*)(vb + ((size_t)b*VV + v) * NPOS + q*256);
    const float4* s4 = (const float4*)(skl + q*256);
    float s = 0.f;
    #pragma unroll 8
    for (int m8 = 0; m8 < 32; ++m8) {
        uint4 wv = v4[m8];
        float4 sa = s4[m8*2], sb = s4[m8*2+1];
        s += sa.x*bflo(wv.x) + sa.y*bfhi(wv.x) + sa.z*bflo(wv.y) + sa.w*bfhi(wv.y)
           + sb.x*bflo(wv.z) + sb.y*bfhi(wv.z) + sb.z*bflo(wv.w) + sb.w*bfhi(wv.w);
    }
    red[t] = s;
    __syncthreads();
    if (q == 0) {
        float r = red[t] + red[t+1] + red[t+2] + red[t+3];
        clb[((size_t)b*VV + v)*16 + kd] = f2bf(r);
    }
}

// ---------------- K4: register-chained MFMA main kernel ----------------
// grid 4096; block 256 = 4 waves. wave: cg = w&1 (4 n's), vf0 = (w>>1)*2 (32 v's).
__global__ __launch_bounds__(256) void k_main(
        const ushort_t* __restrict__ qd, const ushort_t* __restrict__ qc,
        const ushort_t* __restrict__ clb, const ushort_t* __restrict__ vb,
        const ushort_t* __restrict__ E2, float* __restrict__ out) {
    __shared__ ushort_t vb_lds[2][VV][64];   // 16 KB, swizzled chunk image

    const int wg  = blockIdx.x;
    const int b   = (wg >> 3) & 31;
    const int g   = (wg & 7) * 16 + (wg >> 8);
    const int n0  = g * 8;
    const int t   = threadIdx.x;
    const int w   = t >> 6, lane = t & 63;
    const int l15 = lane & 15, l4 = lane >> 4;
    const int cg  = w & 1, vf0 = (w >> 1) << 1;
    const int ncg = g*2 + cg;
    const int swz = (l15 & 7) << 4;

    char* VBc = (char*)&vb_lds[0][0][0];
    char* VBw = VBc + (w*2)*1024;            // wave-uniform DMA dest base

    // ---- loop-invariant operand fragments
    short8 qd0 = *(const short8*)(qd + ((((size_t)b*256 + ncg)*2 + 0)*16 + l15)*32 + l4*8);
    short8 qd1 = *(const short8*)(qd + ((((size_t)b*256 + ncg)*2 + 1)*16 + l15)*32 + l4*8);
    s16x4 qcf  = *(const s16x4*)(qc + (((size_t)b*256 + ncg)*16 + l15)*16 + l4*4);
    s16x4 clf0 = *(const s16x4*)(clb + ((size_t)b*VV + vf0*16 + l15)*16 + l4*4);
    s16x4 clf1 = *(const s16x4*)(clb + ((size_t)b*VV + (vf0+1)*16 + l15)*16 + l4*4);

    const ushort_t* ep = E2 + (size_t)ncg*65536 + l15*64 + l4*8;

    const ushort_t* vb_b = vb + (size_t)b*VV*NPOS;
    const ushort_t* vS0; const ushort_t* vS1;
    {
        int slot0 = (w*2)*64 + lane, slot1 = slot0 + 64;
        int v0_ = slot0 >> 3, c0_ = (slot0 & 7) ^ (v0_ & 7);
        int v1_ = slot1 >> 3, c1_ = (slot1 & 7) ^ (v1_ & 7);
        vS0 = vb_b + (size_t)v0_*NPOS + c0_*8;
        vS1 = vb_b + (size_t)v1_*NPOS + c1_*8;
    }

    #define ELOAD(dst, mtv) do {                                          \
        const ushort_t* _e = ep + (size_t)(mtv)*4096;                     \
        _Pragma("unroll")                                                 \
        for (int _mf = 0; _mf < 4; ++_mf) {                               \
            dst[_mf*2+0] = *(const short8*)(_e + _mf*1024);               \
            dst[_mf*2+1] = *(const short8*)(_e + _mf*1024 + 32);          \
        }                                                                 \
    } while (0)

    #define VSTAGE(mtv, bufsel) do {                                      \
        gload16(vS0 + (mtv)*64, VBw + (bufsel)*8192);                     \
        gload16(vS1 + (mtv)*64, VBw + (bufsel)*8192 + 1024);              \
    } while (0)

    f32x4 acc0 = (f32x4){0.f,0.f,0.f,0.f};
    f32x4 acc1 = (f32x4){0.f,0.f,0.f,0.f};

    const int row0 = vf0*16 + l15, row1 = (vf0+1)*16 + l15;

    #define ITER(eC, eN, mtv, BUF, PF) do {                                    \
        asm volatile("s_waitcnt vmcnt(0)" ::: "memory");                       \
        __builtin_amdgcn_s_barrier();                                          \
        if (PF) { ELOAD(eN, (mtv)+1); VSTAGE((mtv)+1, (BUF)^1); }              \
        __builtin_amdgcn_s_setprio(1);                                         \
        _Pragma("unroll")                                                      \
        for (int mp = 0; mp < 2; ++mp) {                                       \
            f32x4 P0 = (f32x4){0.f,0.f,0.f,0.f};                               \
            P0 = MFMA32(eC[mp*4+0], qd0, P0);                                  \
            P0 = MFMA32(eC[mp*4+1], qd1, P0);                                  \
            f32x4 P1 = (f32x4){0.f,0.f,0.f,0.f};                               \
            P1 = MFMA32(eC[mp*4+2], qd0, P1);                                  \
            P1 = MFMA32(eC[mp*4+3], qd1, P1);                                  \
            short8 pb8 = cat4(pack4(P0), pack4(P1));                           \
            int byA = (mp*64 + l4*8) ^ swz, byB = (mp*64 + 32 + l4*8) ^ swz;   \
            short8 av0 = cat4(                                                 \
                *(const s16x4*)(VBc + (BUF)*8192 + row0*128 + byA),            \
                *(const s16x4*)(VBc + (BUF)*8192 + row0*128 + byB));           \
            short8 av1 = cat4(                                                 \
                *(const s16x4*)(VBc + (BUF)*8192 + row1*128 + byA),            \
                *(const s16x4*)(VBc + (BUF)*8192 + row1*128 + byB));           \
            acc0 = MFMA32(av0, pb8, acc0);                                     \
            acc1 = MFMA32(av1, pb8, acc1);                                     \
        }                                                                      \
        __builtin_amdgcn_s_setprio(0);                                         \
    } while (0)

    short8 eA[8], eB[8];
    ELOAD(eA, 0);
    VSTAGE(0, 0);

    #pragma unroll 1
    for (int mt = 0; mt < 16; mt += 2) {
        ITER(eA, eB, mt,     0, 1);
        ITER(eB, eA, mt + 1, 1, (mt < 14));
    }

    // ---- content term: zero-padded K=32 MFMAs
    {
        s16x4 z4 = (s16x4){0,0,0,0};
        short8 qc8 = cat4(qcf, z4);
        acc0 = MFMA32(cat4(clf0, clf0), qc8, acc0);
        acc1 = MFMA32(cat4(clf1, clf1), qc8, acc1);
    }

    // ---- store: col l15 -> (h = l15&3, n = n0+cg*4+(l15>>2)); row = v
    {
        const int h = l15 & 3;
        const int n = n0 + cg*4 + (l15 >> 2);
        #pragma unroll
        for (int i = 0; i < 4; ++i) {
            int v0_ = vf0*16 + l4*4 + i;
            out[(((size_t)b*HH + h)*VV + v0_)*NPOS + n]      = acc0[i];
            out[(((size_t)b*HH + h)*VV + v0_ + 16)*NPOS + n] = acc1[i];
        }
    }
    #undef ITER
    #undef VSTAGE
    #undef ELOAD
}

// ---------------- launch -------------------
extern "C" void kernel_launch(void* const* d_in, const int* in_sizes, int n_in,
                              void* d_out, int out_size, void* d_ws, size_t ws_size,
                              hipStream_t stream) {
    const float* x  = (const float*)d_in[0];
    const float* Wq = (const float*)d_in[1];
    const float* Wk = (const float*)d_in[2];
    const float* Wv = (const float*)d_in[3];
    const float* E  = (const float*)d_in[4];
    const float* gv = (const float*)d_in[5];
    const float* bv = (const float*)d_in[6];
    const float* gq = (const float*)d_in[7];
    const float* bq = (const float*)d_in[8];
    float* out = (float*)d_out;

    float* ws   = (float*)d_ws;
    float* keys = ws;                          // 524288 f32
    float* vals = keys + 524288;               // 2097152 f32
    float* qrs  = vals + 2097152;              // 2097152 f32
    float* sv   = qrs  + 2097152;              // 2048
    float* sq   = sv   + 2048;                 // 32
    ushort_t* clb = (ushort_t*)(sq + 32);      // 32832 u16
    ushort_t* qd  = clb + 32832;               // 8388608 u16 (16 MB)
    ushort_t* qc  = qd  + 8388608;             // 2097152 u16 (4 MB)
    ushort_t* vbb = qc  + 2097152;             // 2097152 u16 (4 MB)
    ushort_t* E2  = vbb + 2097152;             // 16777216 u16 (32 MB)
    ushort_t* Wb  = E2  + 16777216;            // 36864 u16
    // total ~78 MB of d_ws

    k_zero<<<9, 256, 0, stream>>>(sv, 2048 + 32);
    k_wcvt<<<18, 256, 0, stream>>>(Wq, Wk, Wv, Wb);
    k_projm<<<dim3(BB, 16), 256, 0, stream>>>(x, Wb, keys, vals, qrs);
    k_ecvt2<<<8192, 256, 0, stream>>>(E, E2);
    k_softmax<<<128, 256, 0, stream>>>(keys);
    k_vstats<<<64, 256, 0, stream>>>(vals, sv);
    k_vfinal<<<4, 256, 0, stream>>>(sv, gv, bv);
    k_vcvt<<<1024, 256, 0, stream>>>(vals, sv, vbb);
    k_qstats<<<128, 256, 0, stream>>>(qrs, sq);
    k_qfinal<<<1, 16, 0, stream>>>(sq, gq, bq);
    k_qT<<<512, 256, 0, stream>>>(qrs, sq, qd, qc);
    k_cl<<<512, 256, 0, stream>>>(keys, vbb, clb);
    k_main<<<4096, 256, 0, stream>>>(qd, qc, clb, vbb, E2, out);
}